// Round 7
// baseline (269.986 us; speedup 1.0000x reference)
//
#include <hip/hip_runtime.h>
#include <stdint.h>

#define ENC_D 512
#define ATTN_D 512
#define STR_D 256
#define CELL_D 512
#define BATCH 64
#define SEQ 1024
#define NROWS (BATCH * SEQ)

typedef __bf16 bf16x8 __attribute__((ext_vector_type(8)));
typedef float f32x4 __attribute__((ext_vector_type(4)));

__device__ __forceinline__ unsigned short f2bf(float f) {
    unsigned int u = __float_as_uint(f);
    u += 0x7fffu + ((u >> 16) & 1u);   // RNE
    return (unsigned short)(u >> 16);
}

// native-cast bf16x8 pack: compiler emits v_cvt_pk_bf16_f32 (RNE, identical
// numerics to f2bf — verified r5/r6: absmax unchanged) at ~1/4 the VALU cost.
__device__ __forceinline__ bf16x8 cvt8(const float4 a, const float4 b) {
    bf16x8 r;
    r[0] = (__bf16)a.x; r[1] = (__bf16)a.y; r[2] = (__bf16)a.z; r[3] = (__bf16)a.w;
    r[4] = (__bf16)b.x; r[5] = (__bf16)b.y; r[6] = (__bf16)b.z; r[7] = (__bf16)b.w;
    return r;
}

__device__ __forceinline__ void lds_cp16(void* l, const void* g) {
    __builtin_amdgcn_global_load_lds(
        (const __attribute__((address_space(1))) unsigned int*)g,
        (__attribute__((address_space(3))) unsigned int*)l, 16, 0, 0);
}

// Fused waitcnt+barrier as ONE asm with a memory clobber (compiler fence);
// vmcnt(N) leaves the newest prefetch in flight across the barrier.
#define BAR_VM4() asm volatile("s_waitcnt vmcnt(4)\n\ts_barrier" ::: "memory")
#define BAR_VM0() asm volatile("s_waitcnt vmcnt(0)\n\ts_barrier" ::: "memory")
// Wave-private waits for the A-phase ring (no barrier: waves are decoupled).
#define WAIT_VM8() asm volatile("s_waitcnt vmcnt(8)" ::: "memory")
#define WAIT_VM0() asm volatile("s_waitcnt vmcnt(0)" ::: "memory")

// ---------------------------------------------------------------------------
// Kernel 1 (fused): blocks 0..63   : WF = bf16(W_enc^T) fragment-linear
//                   blocks 64..831 : bias partials [jq][b][a] (12 slabs)
// WF granule (16 B) = 8 k-elems of one column; gi = nt*1024 + ks*64 + quad*16 + c.
// ---------------------------------------------------------------------------
__global__ __launch_bounds__(256) void k_prep(const float* __restrict__ W,
                                              unsigned short* __restrict__ WF,
                                              const float* __restrict__ str,
                                              const float* __restrict__ cell,
                                              const float* __restrict__ Wstr,
                                              const float* __restrict__ Wcell,
                                              float* __restrict__ bpart) {
    __shared__ char smraw[64 * 68 * 2];        // 8704 B, reused per role
    const int bx = blockIdx.x, t = threadIdx.x;

    if (bx < 64) {
        unsigned short* T = (unsigned short*)smraw;   // [n_local][e_local] stride 68
        const int ei = bx >> 3, ni = bx & 7;
        const int e0 = ei * 64, n0 = ni * 64;
#pragma unroll
        for (int i = 0; i < 4; ++i) {
            const int idx = t + i * 256;
            const int r = idx >> 4, c4 = idx & 15;
            const float4 v = *(const float4*)(W + (size_t)(e0 + r) * ATTN_D + n0 + c4 * 4);
            T[(c4 * 4 + 0) * 68 + r] = f2bf(v.x);
            T[(c4 * 4 + 1) * 68 + r] = f2bf(v.y);
            T[(c4 * 4 + 2) * 68 + r] = f2bf(v.z);
            T[(c4 * 4 + 3) * 68 + r] = f2bf(v.w);
        }
        __syncthreads();
#pragma unroll
        for (int i = 0; i < 2; ++i) {
            const int q = t + i * 256;
            const int n = q >> 3, ge = q & 7;
            union { unsigned short s[8]; uint4 u; } o;
#pragma unroll
            for (int j = 0; j < 8; ++j) o.s[j] = T[n * 68 + ge * 8 + j];
            const int ng = n0 + n;
            const int g = ei * 8 + ge;
            const int nt = ng >> 4, c = ng & 15;
            const int ks = g >> 2, quad = g & 3;
            const int gi = nt * 1024 + ks * 64 + quad * 16 + c;
            *(uint4*)(WF + (size_t)gi * 8) = o.u;
        }
    } else {
        float* sj = (float*)smraw;          // 64 floats
        float* red = (float*)smraw + 64;    // 512 floats
        const int q = bx - 64;
        const int b = q / 12, jq = q - b * 12;
        const float* hvec;
        const float* Wbase;
        if (jq < 4) { hvec = str + b * STR_D + jq * 64;         Wbase = Wstr + (size_t)(jq * 64) * ATTN_D; }
        else        { hvec = cell + b * CELL_D + (jq - 4) * 64; Wbase = Wcell + (size_t)((jq - 4) * 64) * ATTN_D; }
        if (t < 64) sj[t] = hvec[t];
        __syncthreads();
        const int h = t >> 7, a4 = t & 127;
        f32x4 acc = {0.f, 0.f, 0.f, 0.f};
#pragma unroll 8
        for (int i = h * 32; i < h * 32 + 32; ++i) {
            const float s = sj[i];
            const float4 wv = *(const float4*)(Wbase + (size_t)i * ATTN_D + a4 * 4);
            acc[0] += s * wv.x; acc[1] += s * wv.y; acc[2] += s * wv.z; acc[3] += s * wv.w;
        }
        if (h == 1) *(f32x4*)(red + a4 * 4) = acc;
        __syncthreads();
        if (h == 0) {
            const f32x4 o = *(const f32x4*)(red + a4 * 4);
            acc[0] += o[0]; acc[1] += o[1]; acc[2] += o[2]; acc[3] += o[3];
            *(f32x4*)(bpart + (size_t)(jq * BATCH + b) * ATTN_D + a4 * 4) = acc;
        }
    }
}

// ---------------------------------------------------------------------------
// Kernel 2: fused scores GEMM + flash-style partial context (r6 structure)
// with a NEW A-phase: E is streamed through LDS via global_load_lds instead
// of VGPR-temp loads. r6 diagnosis: the A-phase was in-flight-limited —
// sustaining the per-CU HBM share (10.25 B/cyc) at ~900 cyc latency needs
// ~9.2 KB in flight/CU, but VGPR-temp loads at 104 VGPR keep only ~2-3 KB
// in flight -> the "21 us" E read actually ran ~50-65 us. global_load_lds
// holds its bytes in the vmcnt queue (no VGPRs): each wave streams its
// 32 rows x 512 cols (64 KB f32) as 8 pieces of 8 KB (32 rows x 64 cols)
// through a wave-private 2 x 8 KB LDS ring; per-wave static vmcnt ledger
// (prologue 16 out; WAIT_VM8 -> piece s landed; read 8 granules -> afr;
// issue piece s+2; s==7 -> WAIT_VM0). No barriers: waves fully decoupled.
// Scatter mapping (verified bijective): granule (issue i, lane) holds
// E[row=(lane&15)+16(i&1)][colq=s*16+(lane>>4)+4(i>>1)] so thread (quad,c)
// finds afr[m][2s+d] at x=d*8+quad*2+j -> (i=m+2(x>>2), lane'=c+16(x&3)).
// In-flight becomes 8-16 KB/wave (~128 KB/CU) -> full HBM BW.
// LDS union: 8 waves x 16 KB A-staging aliases the 96 KB B-ring (+12 KB
// persistent = 143 KB, 1 block/CU). B chunks 0/1 + bias finalize move to
// after the A-phase (one ~2 us L2-resident drain). Loop/softmax/ctx as r6.
// ---------------------------------------------------------------------------
__global__ __launch_bounds__(512, 1) void k_scores(const float* __restrict__ E,
                                                   const unsigned short* __restrict__ WF,
                                                   const float* __restrict__ bpart,
                                                   const float* __restrict__ b_enc,
                                                   const float* __restrict__ b_str,
                                                   const float* __restrict__ b_cell,
                                                   const float* __restrict__ Wcomb,
                                                   float* __restrict__ ctxp,
                                                   float* __restrict__ stats) {
    // union region: [0,131072) = per-wave A-staging (8 x 16 KB), later
    // aliased by the 3 x 32 KB B-ring; [131072,...) persistent.
    __shared__ char smem[131072 + 12352];
    float* sbias = (float*)(smem + 131072);
    float* sWc   = (float*)(smem + 131072 + 2048);
    float* sx    = (float*)(smem + 131072 + 4096);
    float* ex    = (float*)(smem + 131072 + 5120);
    float* redp  = (float*)(smem + 131072 + 6144);   // [3][512]
    float* rtmp  = (float*)(smem + 131072 + 12288);  // [8]

    const int tid = threadIdx.x;
    const int r0 = blockIdx.x * 256;
    const int b = blockIdx.x >> 2;              // 4 blocks per batch
    const int w = tid >> 6, lane = tid & 63;
    const int quad = lane >> 4, c = lane & 15;
    const int rl0 = lane & 15;                  // staging: row-from-lane
    const int cqv = lane >> 4;                  // staging: colq-from-lane

    // ---------------- A-phase: E -> (LDS ring) -> afr registers -----------
    bf16x8 afr[2][16];
    {
        char* Ab = smem + w * 16384;            // wave-private 16 KB (2 x 8 KB)
        const float* Esrc = E + (size_t)(r0 + w * 32) * ENC_D;

#define ISSUE_PIECE(sp)                                                        \
        do {                                                                   \
            char* dst_ = Ab + (((sp) & 1) ? 8192 : 0);                         \
            _Pragma("unroll")                                                  \
            for (int i = 0; i < 8; ++i) {                                      \
                const int row_ = rl0 + ((i & 1) << 4);                         \
                const int colq_ = (sp) * 16 + cqv + ((i >> 1) << 2);           \
                lds_cp16(dst_ + i * 1024 + lane * 16,                          \
                         Esrc + (size_t)row_ * ENC_D + colq_ * 4);             \
            }                                                                  \
        } while (0)

        ISSUE_PIECE(0);
        ISSUE_PIECE(1);
#pragma unroll
        for (int s = 0; s < 8; ++s) {
            if (s < 7) WAIT_VM8();              // piece s landed (newest 8 = s+1)
            else       WAIT_VM0();              // last piece: nothing newer
            const char* Pb = Ab + ((s & 1) ? 8192 : 0);
#pragma unroll
            for (int m = 0; m < 2; ++m)
#pragma unroll
                for (int d = 0; d < 2; ++d) {
                    const int x0 = d * 8 + quad * 2;
                    const int x1 = x0 + 1;
                    const float4 g0 = *(const float4*)(Pb + (m + 2 * (x0 >> 2)) * 1024 + (c + 16 * (x0 & 3)) * 16);
                    const float4 g1 = *(const float4*)(Pb + (m + 2 * (x1 >> 2)) * 1024 + (c + 16 * (x1 & 3)) * 16);
                    afr[m][2 * s + d] = cvt8(g0, g1);
                }
            if (s < 6) ISSUE_PIECE(s + 2);
        }
#undef ISSUE_PIECE
    }

    __syncthreads();   // all waves' A-phases done; staging region reusable

    // ---------------- stage B chunks 0,1 + bias finalize -------------------
#pragma unroll
    for (int p = 0; p < 2; ++p)
#pragma unroll
        for (int i = 0; i < 4; ++i)
            lds_cp16(smem + p * 32768 + i * 8192 + tid * 16,
                     (const char*)WF + (size_t)p * 32768 + i * 8192 + tid * 16);

    if (tid < 128) {
        const int a = tid * 4;
        const float4 be = *(const float4*)(b_enc + a);
        const float4 bs = *(const float4*)(b_str + a);
        const float4 bc = *(const float4*)(b_cell + a);
        f32x4 s;
        s[0] = be.x + bs.x + bc.x; s[1] = be.y + bs.y + bc.y;
        s[2] = be.z + bs.z + bc.z; s[3] = be.w + bs.w + bc.w;
#pragma unroll
        for (int jq = 0; jq < 12; ++jq) {
            const float4 p = *(const float4*)(bpart + (size_t)(jq * BATCH + b) * ATTN_D + a);
            s[0] += p.x; s[1] += p.y; s[2] += p.z; s[3] += p.w;
        }
        *(f32x4*)(sbias + a) = s;
        const float4 wcv = *(const float4*)(Wcomb + a);
        f32x4 wc4; wc4[0] = wcv.x; wc4[1] = wcv.y; wc4[2] = wcv.z; wc4[3] = wcv.w;
        *(f32x4*)(sWc + a) = wc4;
    }

    float sc0[4] = {0.f, 0.f, 0.f, 0.f};
    float sc1[4] = {0.f, 0.f, 0.f, 0.f};

    __syncthreads();   // full drain: B chunks 0,1 staged; sbias/sWc visible

    // ---------------- main loop (r6 structure, vmcnt(4) never-drain) -------
    int cbuf = 0, sbuf = 2;
    for (int ch = 0; ch < 16; ++ch) {
        if (ch < 14) {
            const char* gsrc = (const char*)WF + (size_t)(ch + 2) * 32768;
            char* ldst = smem + sbuf * 32768;
#pragma unroll
            for (int i = 0; i < 4; ++i)
                lds_cp16(ldst + i * 8192 + tid * 16, gsrc + i * 8192 + tid * 16);
        }

        const unsigned short* wb = (const unsigned short*)(smem + cbuf * 32768);
        f32x4 a0e = {0.f,0.f,0.f,0.f}, a0o = {0.f,0.f,0.f,0.f};
        f32x4 a1e = {0.f,0.f,0.f,0.f}, a1o = {0.f,0.f,0.f,0.f};
        f32x4 b0e = {0.f,0.f,0.f,0.f}, b0o = {0.f,0.f,0.f,0.f};
        f32x4 b1e = {0.f,0.f,0.f,0.f}, b1o = {0.f,0.f,0.f,0.f};
#pragma unroll
        for (int ks = 0; ks < 16; ks += 4) {
            const bf16x8 f0 = *(const bf16x8*)(wb + ((ks + 0) * 64 + lane) * 8);
            const bf16x8 f1 = *(const bf16x8*)(wb + ((ks + 1) * 64 + lane) * 8);
            const bf16x8 f2 = *(const bf16x8*)(wb + ((ks + 2) * 64 + lane) * 8);
            const bf16x8 f3 = *(const bf16x8*)(wb + ((ks + 3) * 64 + lane) * 8);
            const bf16x8 g0 = *(const bf16x8*)(wb + 4096 * 2 + ((ks + 0) * 64 + lane) * 8);
            const bf16x8 g1 = *(const bf16x8*)(wb + 4096 * 2 + ((ks + 1) * 64 + lane) * 8);
            const bf16x8 g2 = *(const bf16x8*)(wb + 4096 * 2 + ((ks + 2) * 64 + lane) * 8);
            const bf16x8 g3 = *(const bf16x8*)(wb + 4096 * 2 + ((ks + 3) * 64 + lane) * 8);
            a0e = __builtin_amdgcn_mfma_f32_16x16x32_bf16(afr[0][ks + 0], f0, a0e, 0, 0, 0);
            a1e = __builtin_amdgcn_mfma_f32_16x16x32_bf16(afr[1][ks + 0], f0, a1e, 0, 0, 0);
            a0o = __builtin_amdgcn_mfma_f32_16x16x32_bf16(afr[0][ks + 1], f1, a0o, 0, 0, 0);
            a1o = __builtin_amdgcn_mfma_f32_16x16x32_bf16(afr[1][ks + 1], f1, a1o, 0, 0, 0);
            b0e = __builtin_amdgcn_mfma_f32_16x16x32_bf16(afr[0][ks + 0], g0, b0e, 0, 0, 0);
            b1e = __builtin_amdgcn_mfma_f32_16x16x32_bf16(afr[1][ks + 0], g0, b1e, 0, 0, 0);
            b0o = __builtin_amdgcn_mfma_f32_16x16x32_bf16(afr[0][ks + 1], g1, b0o, 0, 0, 0);
            b1o = __builtin_amdgcn_mfma_f32_16x16x32_bf16(afr[1][ks + 1], g1, b1o, 0, 0, 0);
            a0e = __builtin_amdgcn_mfma_f32_16x16x32_bf16(afr[0][ks + 2], f2, a0e, 0, 0, 0);
            a1e = __builtin_amdgcn_mfma_f32_16x16x32_bf16(afr[1][ks + 2], f2, a1e, 0, 0, 0);
            a0o = __builtin_amdgcn_mfma_f32_16x16x32_bf16(afr[0][ks + 3], f3, a0o, 0, 0, 0);
            a1o = __builtin_amdgcn_mfma_f32_16x16x32_bf16(afr[1][ks + 3], f3, a1o, 0, 0, 0);
            b0e = __builtin_amdgcn_mfma_f32_16x16x32_bf16(afr[0][ks + 2], g2, b0e, 0, 0, 0);
            b1e = __builtin_amdgcn_mfma_f32_16x16x32_bf16(afr[1][ks + 2], g2, b1e, 0, 0, 0);
            b0o = __builtin_amdgcn_mfma_f32_16x16x32_bf16(afr[0][ks + 3], g3, b0o, 0, 0, 0);
            b1o = __builtin_amdgcn_mfma_f32_16x16x32_bf16(afr[1][ks + 3], g3, b1o, 0, 0, 0);
        }

        const int n0 = ch * 32 + c;
        const float bi0 = sbias[n0], wc0 = sWc[n0];
        const float bi1 = sbias[n0 + 16], wc1 = sWc[n0 + 16];
#pragma unroll
        for (int r = 0; r < 4; ++r) {
            float v;
            v = (a0e[r] + a0o[r]) + bi0; sc0[r] += (v > 0.f ? v : 0.f) * wc0;
            v = (b0e[r] + b0o[r]) + bi1; sc0[r] += (v > 0.f ? v : 0.f) * wc1;
            v = (a1e[r] + a1o[r]) + bi0; sc1[r] += (v > 0.f ? v : 0.f) * wc0;
            v = (b1e[r] + b1o[r]) + bi1; sc1[r] += (v > 0.f ? v : 0.f) * wc1;
        }

        cbuf = (cbuf == 2) ? 0 : cbuf + 1;
        sbuf = (sbuf == 2) ? 0 : sbuf + 1;
        if (ch < 15) {
            if (ch < 14) BAR_VM4();
            else         BAR_VM0();
        }
    }

    // reduce across the 16 column-lanes; c==0 lanes hold the row scores
#pragma unroll
    for (int r = 0; r < 4; ++r) {
        float v0 = sc0[r], v1 = sc1[r];
        v0 += __shfl_xor(v0, 1); v1 += __shfl_xor(v1, 1);
        v0 += __shfl_xor(v0, 2); v1 += __shfl_xor(v1, 2);
        v0 += __shfl_xor(v0, 4); v1 += __shfl_xor(v1, 4);
        sc0[r] = v0 + __shfl_xor(v0, 8);
        sc1[r] = v1 + __shfl_xor(v1, 8);
    }
    if (c == 0) {
        const int l0 = w * 32 + quad * 4;
#pragma unroll
        for (int r = 0; r < 4; ++r) sx[l0 + r] = sc0[r];
#pragma unroll
        for (int r = 0; r < 4; ++r) sx[l0 + 16 + r] = sc1[r];
    }
    __syncthreads();

    // ---- block-local softmax partial over this block's 256 rows ----
    if (tid < 256) {
        float v = sx[tid];
        float mm = v;
#pragma unroll
        for (int o = 32; o > 0; o >>= 1) mm = fmaxf(mm, __shfl_xor(mm, o));
        if (lane == 0) rtmp[w] = mm;
    }
    __syncthreads();
    const float m_p = fmaxf(fmaxf(rtmp[0], rtmp[1]), fmaxf(rtmp[2], rtmp[3]));
    if (tid < 256) {
        const float e = __expf(sx[tid] - m_p);
        ex[tid] = e;
        float ss = e;
#pragma unroll
        for (int o = 32; o > 0; o >>= 1) ss += __shfl_xor(ss, o);
        if (lane == 0) rtmp[4 + w] = ss;
    }
    __syncthreads();   // publishes ex[] and partial sums
    if (tid == 0) {
        stats[blockIdx.x * 2 + 0] = m_p;
        stats[blockIdx.x * 2 + 1] = rtmp[4] + rtmp[5] + rtmp[6] + rtmp[7];
    }

    // ---- partial context: ctx_p[512] = sum_l ex[l] * E[r0+l, :] ----
    // 4 row-groups of 64 x 128 col4-threads; E slice re-read f32 (L2/L3-hot).
    // Two independent accumulator chains (even/odd rows), unroll-8.
    {
        const int g = tid >> 7, col4 = tid & 127;
        const float* Ep = E + (size_t)(r0 + g * 64) * ENC_D + col4 * 4;
        f32x4 accA = {0.f, 0.f, 0.f, 0.f};
        f32x4 accB = {0.f, 0.f, 0.f, 0.f};
#pragma unroll 8
        for (int l = 0; l < 64; l += 2) {
            const float4 eA = *(const float4*)(Ep + (size_t)l * ENC_D);
            const float4 eB = *(const float4*)(Ep + (size_t)(l + 1) * ENC_D);
            const float wA = ex[g * 64 + l];
            const float wB = ex[g * 64 + l + 1];
            accA[0] += wA * eA.x; accA[1] += wA * eA.y;
            accA[2] += wA * eA.z; accA[3] += wA * eA.w;
            accB[0] += wB * eB.x; accB[1] += wB * eB.y;
            accB[2] += wB * eB.z; accB[3] += wB * eB.w;
        }
        f32x4 acc;
        acc[0] = accA[0] + accB[0]; acc[1] = accA[1] + accB[1];
        acc[2] = accA[2] + accB[2]; acc[3] = accA[3] + accB[3];
        if (g > 0) *(f32x4*)(redp + (g - 1) * 512 + col4 * 4) = acc;
        __syncthreads();
        if (g == 0) {
            const f32x4 r1 = *(const f32x4*)(redp + 0 * 512 + col4 * 4);
            const f32x4 r2 = *(const f32x4*)(redp + 1 * 512 + col4 * 4);
            const f32x4 r3 = *(const f32x4*)(redp + 2 * 512 + col4 * 4);
            acc[0] += r1[0] + r2[0] + r3[0];
            acc[1] += r1[1] + r2[1] + r3[1];
            acc[2] += r1[2] + r2[2] + r3[2];
            acc[3] += r1[3] + r2[3] + r3[3];
            *(f32x4*)(ctxp + (size_t)blockIdx.x * 512 + col4 * 4) = acc;
        }
    }
}

// ---------------------------------------------------------------------------
// Kernel 3: combine the 4 per-batch partials with max-rescaling.
// ---------------------------------------------------------------------------
__global__ __launch_bounds__(128) void k_final(const float* __restrict__ ctxp,
                                               const float* __restrict__ stats,
                                               float* __restrict__ out) {
    const int b = blockIdx.x, t = threadIdx.x;
    const float m0 = stats[(b * 4 + 0) * 2], z0 = stats[(b * 4 + 0) * 2 + 1];
    const float m1 = stats[(b * 4 + 1) * 2], z1 = stats[(b * 4 + 1) * 2 + 1];
    const float m2 = stats[(b * 4 + 2) * 2], z2 = stats[(b * 4 + 2) * 2 + 1];
    const float m3 = stats[(b * 4 + 3) * 2], z3 = stats[(b * 4 + 3) * 2 + 1];
    const float m = fmaxf(fmaxf(m0, m1), fmaxf(m2, m3));
    const float a0 = __expf(m0 - m), a1 = __expf(m1 - m);
    const float a2 = __expf(m2 - m), a3 = __expf(m3 - m);
    const float invD = 1.f / (z0 * a0 + z1 * a1 + z2 * a2 + z3 * a3);

    const float4 c0 = *(const float4*)(ctxp + (size_t)(b * 4 + 0) * 512 + t * 4);
    const float4 c1 = *(const float4*)(ctxp + (size_t)(b * 4 + 1) * 512 + t * 4);
    const float4 c2 = *(const float4*)(ctxp + (size_t)(b * 4 + 2) * 512 + t * 4);
    const float4 c3 = *(const float4*)(ctxp + (size_t)(b * 4 + 3) * 512 + t * 4);
    f32x4 o;
    o[0] = (c0.x * a0 + c1.x * a1 + c2.x * a2 + c3.x * a3) * invD;
    o[1] = (c0.y * a0 + c1.y * a1 + c2.y * a2 + c3.y * a3) * invD;
    o[2] = (c0.z * a0 + c1.z * a1 + c2.z * a2 + c3.z * a3) * invD;
    o[3] = (c0.w * a0 + c1.w * a1 + c2.w * a2 + c3.w * a3) * invD;
    *(f32x4*)(out + (size_t)b * ENC_D + t * 4) = o;
}

// ---------------------------------------------------------------------------
extern "C" void kernel_launch(void* const* d_in, const int* in_sizes, int n_in,
                              void* d_out, int out_size, void* d_ws, size_t ws_size,
                              hipStream_t stream) {
    const float* E      = (const float*)d_in[0];
    const float* str    = (const float*)d_in[1];
    const float* cell   = (const float*)d_in[2];
    const float* Wenc   = (const float*)d_in[3];
    const float* b_enc  = (const float*)d_in[4];
    const float* Wstr   = (const float*)d_in[5];
    const float* b_str  = (const float*)d_in[6];
    const float* Wcell  = (const float*)d_in[7];
    const float* b_cell = (const float*)d_in[8];
    const float* Wcomb  = (const float*)d_in[9];
    // d_in[10] = b_comb: uniform pre-softmax shift — no effect, skipped.
    float* out = (float*)d_out;

    char* ws = (char*)d_ws;
    unsigned short* WF = (unsigned short*)ws;                  // 512 KB (frag-linear)
    float* bpart = (float*)(ws + (512 << 10));                 // 1.5 MB
    float* ctxp  = (float*)(ws + (512 << 10) + (1536 << 10));  // 512 KB
    float* stats = (float*)(ws + (512 << 10) + (2048 << 10));  // 2 KB

    k_prep<<<832, 256, 0, stream>>>(Wenc, WF, str, cell, Wstr, Wcell, bpart);
    k_scores<<<NROWS / 256, 512, 0, stream>>>(E, WF, bpart, b_enc, b_str, b_cell, Wcomb, ctxp, stats);
    k_final<<<BATCH, 128, 0, stream>>>(ctxp, stats, out);
}